// Round 2
// baseline (544.241 us; speedup 1.0000x reference)
//
#include <hip/hip_runtime.h>
#include <type_traits>

namespace {
constexpr int HH = 512;
constexpr int WW = 512;
constexpr int KS = 11;
constexpr int PADR = 5;
constexpr int TH = 32;                 // tile rows per block
constexpr int TW = 64;                 // tile cols per block
constexpr int SLAB = 16;               // rows processed per phase1/phase2 round
constexpr int HC = TW + 2 * PADR;      // 74: columns incl. horizontal halo
constexpr int LP = 76;                 // LDS pitch: mult of 4 -> 16B-aligned rows
constexpr int NTHREADS = 256;
constexpr float SSIM_C1 = 1.0e-4f;     // (0.01*1.0)^2
constexpr float SSIM_C2 = 9.0e-4f;     // (0.03*1.0)^2
}

// One block per 32x64 output tile, processed as two 16-row slabs so the LDS
// staging buffer is 24.3 KB instead of 48.6 KB -> 6 blocks/CU (24 waves, 75%
// occupancy) instead of 3 (29.7% measured in R1). Phase 1: vertical 11-tap
// blur of {x,y,x^2,y^2,xy} at 16x74 positions into LDS. Phase 2: horizontal
// 11-tap blur + SSIM formula, one float4 group per thread, coalesced store.
__global__ __launch_bounds__(NTHREADS, 6) void ssim_fused(
    const float* __restrict__ x, const float* __restrict__ y,
    const float* __restrict__ kern, float* __restrict__ out)
{
    __shared__ __align__(16) float vb[5][SLAB][LP];   // 24320 B

    constexpr int tiles_w = WW / TW;   // 8
    constexpr int tiles_h = HH / TH;   // 16
    constexpr int tpp = tiles_w * tiles_h;   // 128 tiles per plane

    const int bid = blockIdx.x;
    const int plane = bid / tpp;
    const int trem = bid - plane * tpp;
    const int tr_idx = trem / tiles_w;
    const int tile_r = tr_idx * TH;
    const int tile_c = (trem - tr_idx * tiles_w) * TW;

    const float* __restrict__ xp = x + (size_t)plane * (HH * WW);
    const float* __restrict__ yp = y + (size_t)plane * (HH * WW);
    float* __restrict__ op = out + (size_t)plane * (HH * WW);

    // 1D gaussian from the supplied 2D kernel (exact for outer-product kernels):
    // g[i] = k2d[5][i] / sqrt(k2d[5][5])
    float wt[KS];
    {
        const float c = kern[5 * KS + 5];
        const float inv = rsqrtf(c);
#pragma unroll
        for (int i = 0; i < KS; ++i) wt[i] = kern[5 * KS + i] * inv;
    }

    const int t = threadIdx.x;
    const bool interior = (tile_r >= PADR) && (tile_r + TH + PADR <= HH) &&
                          (tile_c >= PADR) && (tile_c + TW + PADR <= WW);

    // phase-2 mapping: exactly one 4-wide group per thread per slab
    const int p2_r = t >> 4;           // 0..15
    const int p2_c0 = (t & 15) * 4;    // 0..60

    auto run_slab = [&](int s0, auto intr_tag) {
        constexpr bool INTR = decltype(intr_tag)::value;
        // ---- phase 1: vertical blur into LDS (16x74 positions, 4.625/thread)
        for (int i = t; i < SLAB * HC; i += NTHREADS) {
            const int r = i / HC;
            const int c = i - r * HC;
            const int gr = tile_r + s0 + r;     // output row
            const int gc = tile_c + c - PADR;   // input col (maybe OOB on border)
            float sx = 0.f, sy = 0.f, sxx = 0.f, syy = 0.f, sxy = 0.f;
            if (INTR) {
                const float* xq = xp + (size_t)(gr - PADR) * WW + gc;
                const float* yq = yp + (size_t)(gr - PADR) * WW + gc;
#pragma unroll
                for (int k = 0; k < KS; ++k) {
                    const float xv = xq[(size_t)k * WW];
                    const float yv = yq[(size_t)k * WW];
                    const float w = wt[k];
                    sx  += w * xv;
                    sy  += w * yv;
                    sxx += w * xv * xv;
                    syy += w * yv * yv;
                    sxy += w * xv * yv;
                }
            } else {
                const bool cok = (gc >= 0) & (gc < WW);
#pragma unroll
                for (int k = 0; k < KS; ++k) {
                    const int rr = gr - PADR + k;
                    const bool ok = cok & (rr >= 0) & (rr < HH);
                    float xv = 0.f, yv = 0.f;
                    if (ok) {
                        xv = xp[(size_t)rr * WW + gc];
                        yv = yp[(size_t)rr * WW + gc];
                    }
                    const float w = wt[k];
                    sx  += w * xv;
                    sy  += w * yv;
                    sxx += w * xv * xv;
                    syy += w * yv * yv;
                    sxy += w * xv * yv;
                }
            }
            vb[0][r][c] = sx;
            vb[1][r][c] = sy;
            vb[2][r][c] = sxx;
            vb[3][r][c] = syy;
            vb[4][r][c] = sxy;
        }
        __syncthreads();

        // ---- phase 2: horizontal blur + SSIM, 1 float4 group per thread
        float res[5][4];
#pragma unroll
        for (int s = 0; s < 5; ++s) {
            float wnd[KS + 3];
#pragma unroll
            for (int i2 = 0; i2 < KS + 3; ++i2) wnd[i2] = vb[s][p2_r][p2_c0 + i2];
#pragma unroll
            for (int j = 0; j < 4; ++j) {
                float a = 0.f;
#pragma unroll
                for (int k = 0; k < KS; ++k) a += wt[k] * wnd[j + k];
                res[s][j] = a;
            }
        }
        float4 o;
#pragma unroll
        for (int j = 0; j < 4; ++j) {
            const float ux = res[0][j], uy = res[1][j];
            const float uxx = res[2][j], uyy = res[3][j], uxy = res[4][j];
            const float vx  = uxx - ux * ux;
            const float vy  = uyy - uy * uy;
            const float vxy = uxy - ux * uy;
            const float a1 = 2.f * ux * uy + SSIM_C1;
            const float a2 = 2.f * vxy + SSIM_C2;
            const float b1 = ux * ux + uy * uy + SSIM_C1;
            const float b2 = vx + vy + SSIM_C2;
            (&o.x)[j] = (a1 * a2) * __builtin_amdgcn_rcpf(b1 * b2);
        }
        *(float4*)(op + (size_t)(tile_r + s0 + p2_r) * WW + (tile_c + p2_c0)) = o;
        __syncthreads();   // vb reused by next slab
    };

    if (interior) {
        run_slab(0,    std::true_type{});
        run_slab(SLAB, std::true_type{});
    } else {
        run_slab(0,    std::false_type{});
        run_slab(SLAB, std::false_type{});
    }
}

extern "C" void kernel_launch(void* const* d_in, const int* in_sizes, int n_in,
                              void* d_out, int out_size, void* d_ws, size_t ws_size,
                              hipStream_t stream) {
    const float* x    = (const float*)d_in[0];
    const float* y    = (const float*)d_in[1];
    const float* kern = (const float*)d_in[2];
    float* out = (float*)d_out;

    const int nplanes = in_sizes[0] / (HH * WW);            // 48
    const int nblocks = nplanes * (HH / TH) * (WW / TW);    // 6144

    ssim_fused<<<dim3(nblocks), dim3(NTHREADS), 0, stream>>>(x, y, kern, out);
}

// Round 3
// 266.844 us; speedup vs baseline: 2.0396x; 2.0396x over previous
//
#include <hip/hip_runtime.h>
#include <type_traits>

typedef float v2f __attribute__((ext_vector_type(2)));

namespace {
constexpr int HH = 512;
constexpr int WW = 512;
constexpr int KS = 11;
constexpr int PADR = 5;
constexpr int TH = 32;                 // tile rows per block
constexpr int TW = 64;                 // tile cols per block
constexpr int SLAB = 16;               // rows per phase1/phase2 round
constexpr int HC = TW + 2 * PADR;      // 74 columns incl. horizontal halo
constexpr int LPP = 76;                // padded LDS pitch (elements)
constexpr int NTHREADS = 256;
constexpr float SSIM_C1 = 1.0e-4f;     // (0.01*1.0)^2
constexpr float SSIM_C2 = 9.0e-4f;     // (0.03*1.0)^2
}

// One block per 32x64 tile, two 16-row slabs through a 24.3 KB LDS buffer.
// R2 lesson: __launch_bounds__(256,6) forced VGPR=40 -> 1.4 GB scratch spill
// traffic. (256,4) caps at 128 VGPRs: no spill, 4 blocks/CU (50% occupancy).
// Packed fp32: (x,y) and (xx,yy) stat pairs are computed as <2 x float> so
// the backend emits v_pk_{mul,add,fma}_f32 (2 fp32 ops/inst), and are staged
// in LDS interleaved so phase-2 windows are aligned ds_read_b64.
__global__ __launch_bounds__(NTHREADS, 4) void ssim_fused(
    const float* __restrict__ x, const float* __restrict__ y,
    const float* __restrict__ kern, float* __restrict__ out)
{
    __shared__ __align__(16) v2f   vbA[SLAB][LPP];   // (ux, uy)   9728 B
    __shared__ __align__(16) v2f   vbB[SLAB][LPP];   // (uxx, uyy) 9728 B
    __shared__ __align__(16) float vbC[SLAB][LPP];   // uxy        4864 B

    constexpr int tiles_w = WW / TW;         // 8
    constexpr int tiles_h = HH / TH;         // 16
    constexpr int tpp = tiles_w * tiles_h;   // 128 tiles per plane

    const int bid = blockIdx.x;
    const int plane = bid / tpp;
    const int trem = bid - plane * tpp;
    const int tr_idx = trem / tiles_w;
    const int tile_r = tr_idx * TH;
    const int tile_c = (trem - tr_idx * tiles_w) * TW;

    const float* __restrict__ xp = x + (size_t)plane * (HH * WW);
    const float* __restrict__ yp = y + (size_t)plane * (HH * WW);
    float* __restrict__ op = out + (size_t)plane * (HH * WW);

    // 1D gaussian from the 2D kernel (exact for outer products):
    // g[i] = k2d[5][i] / sqrt(k2d[5][5])
    float wt[KS];
    {
        const float c = kern[5 * KS + 5];
        const float inv = rsqrtf(c);
#pragma unroll
        for (int i = 0; i < KS; ++i) wt[i] = kern[5 * KS + i] * inv;
    }

    const int t = threadIdx.x;
    const bool interior = (tile_r >= PADR) && (tile_r + TH + PADR <= HH) &&
                          (tile_c >= PADR) && (tile_c + TW + PADR <= WW);

    // phase-2 mapping: one 4-wide output group per thread per slab
    const int p2_r = t >> 4;           // 0..15
    const int p2_c0 = (t & 15) * 4;    // 0..60

    auto run_slab = [&](int s0, auto intr_tag) {
        constexpr bool INTR = decltype(intr_tag)::value;
        // ---- phase 1: vertical 11-tap blur into LDS (16x74 positions)
        for (int i = t; i < SLAB * HC; i += NTHREADS) {
            const int r = i / HC;
            const int c = i - r * HC;
            const int gr = tile_r + s0 + r;     // output row
            const int gc = tile_c + c - PADR;   // input col (maybe OOB on border)
            v2f s1 = {0.f, 0.f};                // (sum wx, sum wy)
            v2f s2 = {0.f, 0.f};                // (sum wxx, sum wyy)
            float sc = 0.f;                     // sum wxy
            if (INTR) {
                int idx = (gr - PADR) * WW + gc;   // 32-bit element index induction
#pragma unroll
                for (int k = 0; k < KS; ++k) {
                    const float xv = xp[idx];
                    const float yv = yp[idx];
                    idx += WW;
                    v2f v = {xv, yv};
                    v2f p = wt[k] * v;          // v_pk_mul_f32
                    s1 += p;                    // v_pk_add_f32
                    s2 += p * v;                // v_pk_fma_f32
                    sc += p.x * yv;             // v_fmac_f32
                }
            } else {
                const bool cok = (gc >= 0) & (gc < WW);
#pragma unroll
                for (int k = 0; k < KS; ++k) {
                    const int rr = gr - PADR + k;
                    const bool ok = cok & (rr >= 0) & (rr < HH);
                    float xv = 0.f, yv = 0.f;
                    if (ok) {
                        xv = xp[rr * WW + gc];
                        yv = yp[rr * WW + gc];
                    }
                    v2f v = {xv, yv};
                    v2f p = wt[k] * v;
                    s1 += p;
                    s2 += p * v;
                    sc += p.x * yv;
                }
            }
            vbA[r][c] = s1;     // ds_write_b64, lane stride 8 B: conflict-free
            vbB[r][c] = s2;
            vbC[r][c] = sc;
        }
        __syncthreads();

        // ---- phase 2: horizontal 11-tap blur + SSIM, 4 outputs per thread
        v2f uA[4];   // (ux, uy) per output
        v2f uB[4];   // (uxx, uyy)
        float uC[4]; // uxy
        {
            v2f wnd[KS + 3];
#pragma unroll
            for (int i2 = 0; i2 < KS + 3; ++i2) wnd[i2] = vbA[p2_r][p2_c0 + i2];
#pragma unroll
            for (int j = 0; j < 4; ++j) {
                v2f a = {0.f, 0.f};
#pragma unroll
                for (int k = 0; k < KS; ++k) a += wt[k] * wnd[j + k];  // v_pk_fma
                uA[j] = a;
            }
        }
        {
            v2f wnd[KS + 3];
#pragma unroll
            for (int i2 = 0; i2 < KS + 3; ++i2) wnd[i2] = vbB[p2_r][p2_c0 + i2];
#pragma unroll
            for (int j = 0; j < 4; ++j) {
                v2f a = {0.f, 0.f};
#pragma unroll
                for (int k = 0; k < KS; ++k) a += wt[k] * wnd[j + k];
                uB[j] = a;
            }
        }
        {
            float wnd[KS + 3];
#pragma unroll
            for (int i2 = 0; i2 < KS + 3; ++i2) wnd[i2] = vbC[p2_r][p2_c0 + i2];
#pragma unroll
            for (int j = 0; j < 4; ++j) {
                float a = 0.f;
#pragma unroll
                for (int k = 0; k < KS; ++k) a += wt[k] * wnd[j + k];
                uC[j] = a;
            }
        }
        float4 o;
#pragma unroll
        for (int j = 0; j < 4; ++j) {
            const float ux = uA[j].x, uy = uA[j].y;
            const float uxx = uB[j].x, uyy = uB[j].y, uxy = uC[j];
            const float vx  = uxx - ux * ux;
            const float vy  = uyy - uy * uy;
            const float vxy = uxy - ux * uy;
            const float a1 = 2.f * ux * uy + SSIM_C1;
            const float a2 = 2.f * vxy + SSIM_C2;
            const float b1 = ux * ux + uy * uy + SSIM_C1;
            const float b2 = vx + vy + SSIM_C2;
            (&o.x)[j] = (a1 * a2) * __builtin_amdgcn_rcpf(b1 * b2);
        }
        *(float4*)(op + (size_t)(tile_r + s0 + p2_r) * WW + (tile_c + p2_c0)) = o;
        __syncthreads();   // LDS reused by next slab
    };

    if (interior) {
        run_slab(0,    std::true_type{});
        run_slab(SLAB, std::true_type{});
    } else {
        run_slab(0,    std::false_type{});
        run_slab(SLAB, std::false_type{});
    }
}

extern "C" void kernel_launch(void* const* d_in, const int* in_sizes, int n_in,
                              void* d_out, int out_size, void* d_ws, size_t ws_size,
                              hipStream_t stream) {
    const float* x    = (const float*)d_in[0];
    const float* y    = (const float*)d_in[1];
    const float* kern = (const float*)d_in[2];
    float* out = (float*)d_out;

    const int nplanes = in_sizes[0] / (HH * WW);            // 48
    const int nblocks = nplanes * (HH / TH) * (WW / TW);    // 6144

    ssim_fused<<<dim3(nblocks), dim3(NTHREADS), 0, stream>>>(x, y, kern, out);
}

// Round 4
// 227.400 us; speedup vs baseline: 2.3933x; 1.1735x over previous
//
#include <hip/hip_runtime.h>
#include <type_traits>

namespace {
constexpr int HH = 512;
constexpr int WW = 512;
constexpr int KS = 11;
constexpr int PADR = 5;
constexpr int TH = 32;                 // tile rows per block
constexpr int TW = 64;                 // tile cols per block
constexpr int SLAB = 16;               // rows per phase1/phase2 round
constexpr int HC = TW + 2 * PADR;      // 74 columns incl. horizontal halo
constexpr int LP = 77;                 // pitch 77: phase-2 rows land in distinct
                                       // bank classes mod 4 -> 2-way (free)
constexpr int NTHREADS = 256;
constexpr float SSIM_C1 = 1.0e-4f;     // (0.01*1.0)^2
constexpr float SSIM_C2 = 9.0e-4f;     // (0.03*1.0)^2
}

// R1 scalar code (known-good codegen: 142us, VALUBusy 62%) + exactly two
// counter-justified fixes:
//  - two 16-row slabs through a 24.6 KB LDS buffer (R1's 48.6 KB capped
//    occupancy at 3 blocks/CU = 29.7%); launch_bounds(256,4) caps VGPR at
//    128 -- far above the ~80 this code needs, so no R2-style spill.
//  - LDS pitch 76->77 kills the 8-way phase-2 bank conflict (1.14e7 cycles
//    in R1): lane first-bank = 4*(t&15) + 13*(t>>4) mod 32 covers all 32
//    banks exactly 2-way, which is free.
__global__ __launch_bounds__(NTHREADS, 4) void ssim_fused(
    const float* __restrict__ x, const float* __restrict__ y,
    const float* __restrict__ kern, float* __restrict__ out)
{
    __shared__ float vb[5][SLAB][LP];   // 24640 B

    constexpr int tiles_w = WW / TW;         // 8
    constexpr int tiles_h = HH / TH;         // 16
    constexpr int tpp = tiles_w * tiles_h;   // 128 tiles per plane

    const int bid = blockIdx.x;
    const int plane = bid / tpp;
    const int trem = bid - plane * tpp;
    const int tr_idx = trem / tiles_w;
    const int tile_r = tr_idx * TH;
    const int tile_c = (trem - tr_idx * tiles_w) * TW;

    const float* __restrict__ xp = x + (size_t)plane * (HH * WW);
    const float* __restrict__ yp = y + (size_t)plane * (HH * WW);
    float* __restrict__ op = out + (size_t)plane * (HH * WW);

    // 1D gaussian from the 2D kernel (exact for outer products):
    // g[i] = k2d[5][i] / sqrt(k2d[5][5])
    float wt[KS];
    {
        const float c = kern[5 * KS + 5];
        const float inv = rsqrtf(c);
#pragma unroll
        for (int i = 0; i < KS; ++i) wt[i] = kern[5 * KS + i] * inv;
    }

    const int t = threadIdx.x;
    const bool interior = (tile_r >= PADR) && (tile_r + TH + PADR <= HH) &&
                          (tile_c >= PADR) && (tile_c + TW + PADR <= WW);

    // phase-2 mapping: one 4-wide output group per thread per slab
    const int p2_r = t >> 4;           // 0..15
    const int p2_c0 = (t & 15) * 4;    // 0..60

    auto run_slab = [&](int s0, auto intr_tag) {
        constexpr bool INTR = decltype(intr_tag)::value;
        // ---- phase 1: vertical 11-tap blur into LDS (16x74 positions)
        for (int i = t; i < SLAB * HC; i += NTHREADS) {
            const int r = i / HC;
            const int c = i - r * HC;
            const int gr = tile_r + s0 + r;     // output row
            const int gc = tile_c + c - PADR;   // input col (maybe OOB on border)
            float sx = 0.f, sy = 0.f, sxx = 0.f, syy = 0.f, sxy = 0.f;
            if (INTR) {
                const float* xq = xp + (gr - PADR) * WW + gc;
                const float* yq = yp + (gr - PADR) * WW + gc;
#pragma unroll
                for (int k = 0; k < KS; ++k) {
                    const float xv = xq[k * WW];
                    const float yv = yq[k * WW];
                    const float w = wt[k];
                    sx  += w * xv;
                    sy  += w * yv;
                    sxx += w * xv * xv;
                    syy += w * yv * yv;
                    sxy += w * xv * yv;
                }
            } else {
                const bool cok = (gc >= 0) & (gc < WW);
#pragma unroll
                for (int k = 0; k < KS; ++k) {
                    const int rr = gr - PADR + k;
                    const bool ok = cok & (rr >= 0) & (rr < HH);
                    float xv = 0.f, yv = 0.f;
                    if (ok) {
                        xv = xp[rr * WW + gc];
                        yv = yp[rr * WW + gc];
                    }
                    const float w = wt[k];
                    sx  += w * xv;
                    sy  += w * yv;
                    sxx += w * xv * xv;
                    syy += w * yv * yv;
                    sxy += w * xv * yv;
                }
            }
            vb[0][r][c] = sx;
            vb[1][r][c] = sy;
            vb[2][r][c] = sxx;
            vb[3][r][c] = syy;
            vb[4][r][c] = sxy;
        }
        __syncthreads();

        // ---- phase 2: horizontal 11-tap blur + SSIM, 4 outputs per thread
        float res[5][4];
#pragma unroll
        for (int s = 0; s < 5; ++s) {
            float wnd[KS + 3];
#pragma unroll
            for (int i2 = 0; i2 < KS + 3; ++i2) wnd[i2] = vb[s][p2_r][p2_c0 + i2];
#pragma unroll
            for (int j = 0; j < 4; ++j) {
                float a = 0.f;
#pragma unroll
                for (int k = 0; k < KS; ++k) a += wt[k] * wnd[j + k];
                res[s][j] = a;
            }
        }
        float4 o;
#pragma unroll
        for (int j = 0; j < 4; ++j) {
            const float ux = res[0][j], uy = res[1][j];
            const float uxx = res[2][j], uyy = res[3][j], uxy = res[4][j];
            const float vx  = uxx - ux * ux;
            const float vy  = uyy - uy * uy;
            const float vxy = uxy - ux * uy;
            const float a1 = 2.f * ux * uy + SSIM_C1;
            const float a2 = 2.f * vxy + SSIM_C2;
            const float b1 = ux * ux + uy * uy + SSIM_C1;
            const float b2 = vx + vy + SSIM_C2;
            (&o.x)[j] = (a1 * a2) * __builtin_amdgcn_rcpf(b1 * b2);
        }
        *(float4*)(op + (size_t)(tile_r + s0 + p2_r) * WW + (tile_c + p2_c0)) = o;
        __syncthreads();   // LDS reused by next slab
    };

    if (interior) {
        run_slab(0,    std::true_type{});
        run_slab(SLAB, std::true_type{});
    } else {
        run_slab(0,    std::false_type{});
        run_slab(SLAB, std::false_type{});
    }
}

extern "C" void kernel_launch(void* const* d_in, const int* in_sizes, int n_in,
                              void* d_out, int out_size, void* d_ws, size_t ws_size,
                              hipStream_t stream) {
    const float* x    = (const float*)d_in[0];
    const float* y    = (const float*)d_in[1];
    const float* kern = (const float*)d_in[2];
    float* out = (float*)d_out;

    const int nplanes = in_sizes[0] / (HH * WW);            // 48
    const int nblocks = nplanes * (HH / TH) * (WW / TW);    // 6144

    ssim_fused<<<dim3(nblocks), dim3(NTHREADS), 0, stream>>>(x, y, kern, out);
}